// Round 12
// baseline (189.589 us; speedup 1.0000x reference)
//
#include <hip/hip_runtime.h>
#include <hip/hip_bf16.h>
#include <hip/hip_fp16.h>
#include <stdint.h>

#define NNODES 100000
#define HID 128
#define NEDGES 1000000
#define NEBLOCKS 15625  // edge blocks: 15625 * 4 waves * 16 edges = 1,000,000

typedef __attribute__((ext_vector_type(4))) float floatx4;
typedef _Float16 f16x2 __attribute__((ext_vector_type(2)));
typedef _Float16 f16x4 __attribute__((ext_vector_type(4)));
typedef _Float16 f16x8 __attribute__((ext_vector_type(8)));

// ---------------- Kernel 1: node projection via single-pass f16 MFMA -------
// Block: 64 rows x 256 cols. Staging: fully-coalesced flat copy of emb
// (fp32->f16 in-register), LDS As stride 136 halfs. One barrier, then K-loop:
// A via ds_read_b128; B fragments built DIRECTLY from W1 (8 strided dword
// loads per fragment, L2-hot 128KB, wave-uniform half selection) — no pack
// kernel. 64 MFMA/wave. P fp16 store via Co-LDS (aliased) epilogue.
__global__ __launch_bounds__(256) void project_kernel(
    const float* __restrict__ emb, const float* __restrict__ W1,
    __half* __restrict__ P) {
  __shared__ __align__(16) char smem[64 * 264 * 2];  // 33792 B
  _Float16* As = (_Float16*)smem;  // [row][k], stride 136 halfs
  __half* Co = (__half*)smem;      // alias after K-loop, 64 x 264

  const int t = threadIdx.x;
  const int lane = t & 63;
  const int w = t >> 6;
  const int l16 = lane & 15;
  const int q = lane >> 4;
  const int row0 = blockIdx.x * 64;

  // ---- staging: iter i covers flat float idx t*4 + i*1024 (wave-contiguous)
  {
    const int r_base = t >> 5;       // 0..7
    const int col = (t & 31) * 4;    // 0..124
#pragma unroll
    for (int i = 0; i < 8; ++i) {
      int grow = row0 + r_base + i * 8;
      if (grow >= NNODES) grow = NNODES - 1;  // tail-block clamp
      const floatx4 v = *(const floatx4*)(emb + (size_t)grow * HID + col);
      f16x4 h;
      h[0] = (_Float16)v.x; h[1] = (_Float16)v.y;
      h[2] = (_Float16)v.z; h[3] = (_Float16)v.w;
      *(f16x4*)&As[(r_base + i * 8) * 136 + col] = h;
    }
  }

  // wave-uniform B column base: cols w*64.. -> top half (W1[k][n], k=0..127)
  // for w<2, bottom half (W1[128+k][n-128]) for w>=2.
  const int n0 = w * 64 + l16;  // + ct*16 added per fragment
  const float* bbase = (w < 2) ? (W1 + n0) : (W1 + (size_t)HID * HID + (n0 - HID));

  __syncthreads();

  floatx4 acc[4][4] = {};  // [rt][ct]
#pragma unroll
  for (int ks = 0; ks < 4; ++ks) {
    const int kbase = ks * 32 + q * 8;
    f16x8 bh[4];
#pragma unroll
    for (int ct = 0; ct < 4; ++ct) {
      const float* bp = bbase + ct * 16 + (size_t)kbase * HID;
      f16x8 b;
#pragma unroll
      for (int j = 0; j < 8; ++j) b[j] = (_Float16)bp[(size_t)j * HID];
      bh[ct] = b;
    }
    f16x8 ah[4];
#pragma unroll
    for (int rt = 0; rt < 4; ++rt)
      ah[rt] = *(const f16x8*)&As[(rt * 16 + l16) * 136 + ks * 32 + q * 8];
#pragma unroll
    for (int rt = 0; rt < 4; ++rt)
#pragma unroll
      for (int ct = 0; ct < 4; ++ct)
        acc[rt][ct] = __builtin_amdgcn_mfma_f32_16x16x32_f16(ah[rt], bh[ct], acc[rt][ct], 0, 0, 0);
  }

  // epilogue: C/D layout col=lane&15, row=(lane>>4)*4+reg -> LDS -> coalesced.
  __syncthreads();  // As reads done; safe to alias Co
#pragma unroll
  for (int rt = 0; rt < 4; ++rt)
#pragma unroll
    for (int ct = 0; ct < 4; ++ct)
#pragma unroll
      for (int r = 0; r < 4; ++r) {
        const int row = rt * 16 + q * 4 + r;
        const int col = w * 64 + ct * 16 + l16;
        Co[row * 264 + col] = __float2half(acc[rt][ct][r]);
      }
  __syncthreads();
#pragma unroll
  for (int i = 0; i < 8; ++i) {
    const int chunk = t + i * 256;  // 2048 chunks of 16B, 32 per row
    const int row = chunk >> 5;
    const int cx = chunk & 31;
    if (row0 + row < NNODES) {
      const floatx4 v = *(const floatx4*)&Co[row * 264 + cx * 8];
      *(floatx4*)(P + (size_t)(row0 + row) * 256 + cx * 8) = v;
    }
  }
}

// ---------------- Kernel 2: per-edge MLP + exp --------------------
// Exact-fit grid: 15625 blocks x 4 waves x 16 edges = 1,000,000. No loop,
// no bounds checks. 16 lanes/edge, 8 halfs/lane (dwordx4 gathers),
// packed-half math + v_dot2_f32_f16, 4-shuffle reduce per 4 edges.
// Block partial sum -> plain store to partials[blockIdx.x] (no atomics).
__global__ __launch_bounds__(256) void edge_kernel(
    const __half* __restrict__ P, const int* __restrict__ lm,
    const float* __restrict__ b1, const float* __restrict__ W2,
    const float* __restrict__ b2, float* __restrict__ explog,
    float* __restrict__ partials) {
  const int lane = threadIdx.x & 63;
  const int wid = threadIdx.x >> 6;
  const int g = lane >> 4;    // edge sub-group 0..3
  const int l16 = lane & 15;
  const int c = l16 * 8;      // 8 halfs per lane

  f16x2 b1h[4], w2h[4];
  {
    const floatx4 b1a = *(const floatx4*)(b1 + c);
    const floatx4 b1b = *(const floatx4*)(b1 + c + 4);
    const floatx4 w2a = *(const floatx4*)(W2 + c);
    const floatx4 w2b = *(const floatx4*)(W2 + c + 4);
    b1h[0] = f16x2{(_Float16)b1a.x, (_Float16)b1a.y};
    b1h[1] = f16x2{(_Float16)b1a.z, (_Float16)b1a.w};
    b1h[2] = f16x2{(_Float16)b1b.x, (_Float16)b1b.y};
    b1h[3] = f16x2{(_Float16)b1b.z, (_Float16)b1b.w};
    w2h[0] = f16x2{(_Float16)w2a.x, (_Float16)w2a.y};
    w2h[1] = f16x2{(_Float16)w2a.z, (_Float16)w2a.w};
    w2h[2] = f16x2{(_Float16)w2b.x, (_Float16)w2b.y};
    w2h[3] = f16x2{(_Float16)w2b.z, (_Float16)w2b.w};
  }
  const f16x2 z2 = {(_Float16)0.f, (_Float16)0.f};
  const float b2v = b2[0];

  const int e0 = (blockIdx.x * 4 + wid) * 16;

  uint4 rs[4], rt_[4];
#pragma unroll
  for (int j = 0; j < 4; ++j) {
    const int ej = e0 + j * 4 + g;
    const int src = lm[ej];
    const int tgt = lm[NEDGES + ej];
    rs[j]  = *(const uint4*)(P + (size_t)src * 256 + c);
    rt_[j] = *(const uint4*)(P + (size_t)tgt * 256 + 128 + c);
  }
  float lsum = 0.f;
#pragma unroll
  for (int j = 0; j < 4; ++j) {
    float p = 0.f;
    const unsigned su[4] = {rs[j].x, rs[j].y, rs[j].z, rs[j].w};
    const unsigned tu[4] = {rt_[j].x, rt_[j].y, rt_[j].z, rt_[j].w};
#pragma unroll
    for (int h = 0; h < 4; ++h) {
      const f16x2 s = __builtin_bit_cast(f16x2, su[h]);
      const f16x2 tt = __builtin_bit_cast(f16x2, tu[h]);
      const f16x2 a = __builtin_elementwise_max(s + tt + b1h[h], z2);
      p = __builtin_amdgcn_fdot2(a, w2h[h], p, false);
    }
    p += __shfl_xor(p, 8, 64);
    p += __shfl_xor(p, 4, 64);
    p += __shfl_xor(p, 2, 64);
    p += __shfl_xor(p, 1, 64);
    if (l16 == j) {
      const float ev = __expf(p + b2v);
      explog[e0 + j * 4 + g] = ev;
      lsum += ev;
    }
  }

#pragma unroll
  for (int off = 32; off >= 1; off >>= 1) lsum += __shfl_xor(lsum, off, 64);
  __shared__ float wsums[4];
  if (lane == 0) wsums[wid] = lsum;
  __syncthreads();
  if (threadIdx.x == 0)
    partials[blockIdx.x] = wsums[0] + wsums[1] + wsums[2] + wsums[3];
}

// ---------------- Kernel 3: fused reduce + normalize ----------------
// Each block redundantly sums the 15625 partials (62.5 KB, L2-hot across the
// 977 blocks) -> total, then normalizes its 1024-float slice of the output.
__global__ __launch_bounds__(256) void norm_kernel(
    const float* __restrict__ explog, const float* __restrict__ partials,
    float* __restrict__ out) {
  const int t = threadIdx.x;
  float s = 0.f;
  for (int i = t; i < 3906; i += 256) {  // 3906 float4 chunks
    const floatx4 v = *(const floatx4*)(partials + i * 4);
    s += (v.x + v.y) + (v.z + v.w);
  }
  if (t == 0) s += partials[15624];
#pragma unroll
  for (int off = 32; off >= 1; off >>= 1) s += __shfl_xor(s, off, 64);
  __shared__ float ws_[4];
  if ((t & 63) == 0) ws_[t >> 6] = s;
  __syncthreads();
  const float inv = 1.0f / (ws_[0] + ws_[1] + ws_[2] + ws_[3]);

  const int i = (blockIdx.x * 256 + t) * 4;
  if (i < NEDGES) {
    floatx4 v = *(const floatx4*)(explog + i);
    v.x *= inv; v.y *= inv; v.z *= inv; v.w *= inv;
    *(floatx4*)(out + i) = v;
  }
}

extern "C" void kernel_launch(void* const* d_in, const int* in_sizes, int n_in,
                              void* d_out, int out_size, void* d_ws, size_t ws_size,
                              hipStream_t stream) {
  const float* emb = (const float*)d_in[0];
  const int*   lm  = (const int*)d_in[1];   // [2, 1M]: sources then targets
  const float* W1  = (const float*)d_in[2];
  const float* b1  = (const float*)d_in[3];
  const float* W2  = (const float*)d_in[4];
  const float* b2  = (const float*)d_in[5];
  float* out = (float*)d_out;

  char* ws = (char*)d_ws;
  __half* P       = (__half*)ws;                   // 51,200,000 B
  float* explog   = (float*)(ws + 51200000);       // 4,000,000 B
  float* partials = (float*)(ws + 55200000);       // 15625*4 B

  project_kernel<<<1563, 256, 0, stream>>>(emb, W1, P);  // 1563*64 >= 100000
  edge_kernel<<<NEBLOCKS, 256, 0, stream>>>(P, lm, b1, W2, b2, explog, partials);
  norm_kernel<<<977, 256, 0, stream>>>(explog, partials, out);
}